// Round 1
// baseline (1129.419 us; speedup 1.0000x reference)
//
#include <hip/hip_runtime.h>
#include <stdint.h>

#define T_TOKENS 4096
#define D_DIM 768
#define H_DIM 1536
#define NEXP 64
#define TOPK 6
#define CAP 1536
#define MAXTILES 288          // bound: (24576 + 64*127 + 4096)/128 = 287.5
#define MAXROWS (MAXTILES*128)

typedef __bf16 bf16x8 __attribute__((ext_vector_type(8)));
typedef float f32x4 __attribute__((ext_vector_type(4)));

__device__ __forceinline__ ushort f2bf(float f) {
    union { float f; uint32_t u; } v; v.f = f;
    uint32_t r = v.u + 0x7FFFu + ((v.u >> 16) & 1u);   // RNE
    return (ushort)(r >> 16);
}

// ---------------------------------------------------------------- gate ------
__global__ __launch_bounds__(256)
void gate_kernel(const float* __restrict__ x, const float* __restrict__ gate_w,
                 int* __restrict__ cnt, float* __restrict__ prob_sum,
                 int* __restrict__ tok_of, float* __restrict__ sc_of)
{
    __shared__ float xs[16 * 768];
    __shared__ float sred[4][64];
    const int tid = threadIdx.x;
    const int t0 = blockIdx.x * 16;
    const float4* xg = (const float4*)(x + (size_t)t0 * 768);
    float4* xs4w = (float4*)xs;
    #pragma unroll
    for (int c = 0; c < 12; ++c) xs4w[c * 256 + tid] = xg[c * 256 + tid];
    __syncthreads();
    const int lane = tid & 63;
    const int wv = tid >> 6;
    float dots[4] = {0.f, 0.f, 0.f, 0.f};
    const float4* w4 = (const float4*)(gate_w + (size_t)lane * 768);
    const float4* xs4 = (const float4*)xs;
    for (int d = 0; d < 192; ++d) {
        float4 w = w4[d];
        #pragma unroll
        for (int tt = 0; tt < 4; ++tt) {
            float4 xv = xs4[(wv * 4 + tt) * 192 + d];
            dots[tt] += w.x * xv.x + w.y * xv.y + w.z * xv.z + w.w * xv.w;
        }
    }
    float psum_local = 0.f;
    for (int tt = 0; tt < 4; ++tt) {
        const int t = t0 + wv * 4 + tt;
        float z = dots[tt];
        float m = z;
        #pragma unroll
        for (int off = 32; off; off >>= 1) m = fmaxf(m, __shfl_xor(m, off));
        float ex = expf(z - m);
        float s = ex;
        #pragma unroll
        for (int off = 32; off; off >>= 1) s += __shfl_xor(s, off);
        float p = ex / s;
        psum_local += p;
        float pv = p;                       // this lane's candidate (own expert)
        for (int k = 0; k < TOPK; ++k) {
            float v = pv; int widx = lane;
            #pragma unroll
            for (int off = 32; off; off >>= 1) {
                float ov = __shfl_xor(v, off);
                int oi = __shfl_xor(widx, off);
                if (ov > v || (ov == v && oi < widx)) { v = ov; widx = oi; }
            }
            if (lane == widx) {
                int pos = atomicAdd(&cnt[lane], 1);
                if (pos < CAP) { tok_of[lane * CAP + pos] = t; sc_of[lane * CAP + pos] = p; }
                pv = -1.0f;
            }
        }
    }
    sred[wv][lane] = psum_local;
    __syncthreads();
    if (wv == 0) {
        float tot = sred[0][lane] + sred[1][lane] + sred[2][lane] + sred[3][lane];
        atomicAdd(&prob_sum[lane], tot);
    }
}

// --------------------------------------------------------------- stats ------
__global__ void stats_kernel(const int* __restrict__ cnt, const float* __restrict__ prob_sum,
                             int* __restrict__ off, int* __restrict__ d_total_tiles,
                             int* __restrict__ tile_expert, float* __restrict__ out_tail)
{
    __shared__ int soff[66];
    __shared__ float sfp[64];
    const int tid = threadIdx.x;
    if (tid == 0) {
        int o = 0;
        for (int e = 0; e < NEXP; ++e) {
            soff[e] = o;
            int c = cnt[e]; if (c > CAP) c = CAP;
            o += ((c + 127) >> 7) << 7;          // 128-align each expert
        }
        soff[64] = o;                            // shared expert (count T_TOKENS)
        soff[65] = o + T_TOKENS;
        *d_total_tiles = (o + T_TOKENS) >> 7;
    }
    __syncthreads();
    if (tid < 66) off[tid] = soff[tid];
    const int total = soff[65] >> 7;
    for (int tile = tid; tile < MAXTILES; tile += blockDim.x) {
        if (tile < total) {
            int e = 0;
            for (int q = 1; q < 65; ++q) if (soff[q] <= tile * 128) e = q;
            tile_expert[tile] = e;
        }
    }
    if (tid < 64) {
        float f  = (float)cnt[tid] * (1.0f / 24576.0f);
        float pr = prob_sum[tid] * (1.0f / 4096.0f);
        out_tail[1 + tid] = f;
        out_tail[1 + 64 + tid] = pr;
        sfp[tid] = f * pr;
    }
    __syncthreads();
    if (tid == 0) {
        float l = 0.f;
        for (int e = 0; e < NEXP; ++e) l += sfp[e];
        out_tail[0] = 0.01f * l;
    }
}

// -------------------------------------------------------------- gather ------
__global__ __launch_bounds__(192)
void gather_kernel(const float* __restrict__ x,
                   const int* __restrict__ off, const int* __restrict__ cnt,
                   const int* __restrict__ tile_expert, const int* __restrict__ d_total_tiles,
                   const int* __restrict__ tok_of, const float* __restrict__ sc_of,
                   ushort* __restrict__ Xg, int* __restrict__ row_tok, float* __restrict__ row_score)
{
    const int row = blockIdx.x;
    if (row >= (*d_total_tiles) * 128) return;
    const int e = tile_expert[row >> 7];
    const int r = row - off[e];
    int t = 0; float sc = 0.f; bool real = false;
    if (e == NEXP) { t = r; sc = 1.0f; real = true; }
    else {
        int c = cnt[e]; if (c > CAP) c = CAP;
        if (r < c) { t = tok_of[e * CAP + r]; sc = sc_of[e * CAP + r]; real = true; }
    }
    const int tid = threadIdx.x;                 // 192 threads x float4 = 768
    ushort4* dst = (ushort4*)(Xg + (size_t)row * 768);
    if (real) {
        float4 v = ((const float4*)(x + (size_t)t * 768))[tid];
        ushort4 o; o.x = f2bf(v.x); o.y = f2bf(v.y); o.z = f2bf(v.z); o.w = f2bf(v.w);
        dst[tid] = o;
    } else {
        dst[tid] = make_ushort4(0, 0, 0, 0);
    }
    if (tid == 0) { row_tok[row] = t; row_score[row] = real ? sc : 0.0f; }
}

// ---------------------------------------------------------------- gemm ------
// C[128m x 128n] = act(A @ W^T + b); A bf16 [rows,KD], W fp32 [ND,KD] row-major.
template<int KD, int ND, bool DOGELU>
__global__ __launch_bounds__(256, 2)
void gemm_kernel(const ushort* __restrict__ Abuf,
                 const float* __restrict__ Wexp, const float* __restrict__ Wsh,
                 const float* __restrict__ Bexp, const float* __restrict__ Bsh,
                 const int* __restrict__ d_total_tiles, const int* __restrict__ tile_expert,
                 ushort* __restrict__ Hout, float* __restrict__ Cout,
                 const int* __restrict__ row_tok, const float* __restrict__ row_score)
{
    const int mt = blockIdx.x;
    if (mt >= *d_total_tiles) return;
    const int e = tile_expert[mt];
    const float* W  = (e < NEXP) ? (Wexp + (size_t)e * ND * KD) : Wsh;
    const float* Bi = (e < NEXP) ? (Bexp + (size_t)e * ND) : Bsh;
    const int row0 = mt * 128;
    const int n0 = blockIdx.y * 128;

    __shared__ ushort sA[128][72];   // BK=64, +8 pad (16B-aligned rows, 144B stride)
    __shared__ ushort sB[128][72];

    const int tid = threadIdx.x;
    const int lane = tid & 63;
    const int wv = tid >> 6;
    const int wm = (wv >> 1) << 6;
    const int wn = (wv & 1) << 6;
    const int lm = lane & 15;
    const int lq = lane >> 4;

    f32x4 acc[4][4] = {};

    for (int ks = 0; ks < KD / 64; ++ks) {
        const int k0 = ks * 64;
        #pragma unroll
        for (int c = 0; c < 4; ++c) {            // A: 128x64 bf16 (1024 x 16B)
            int idx = c * 256 + tid;
            int r = idx >> 3;
            int c8 = (idx & 7) << 3;
            uint4 v = *(const uint4*)(Abuf + (size_t)(row0 + r) * KD + (k0 + c8));
            *(uint4*)&sA[r][c8] = v;
        }
        #pragma unroll
        for (int c = 0; c < 8; ++c) {            // W: 128x64 fp32 -> bf16
            int idx = c * 256 + tid;
            int r = idx >> 4;
            int c4 = (idx & 15) << 2;
            float4 wv4 = *(const float4*)(W + (size_t)(n0 + r) * KD + (k0 + c4));
            ushort4 h4;
            h4.x = f2bf(wv4.x); h4.y = f2bf(wv4.y); h4.z = f2bf(wv4.z); h4.w = f2bf(wv4.w);
            *(ushort4*)&sB[r][c4] = h4;
        }
        __syncthreads();
        #pragma unroll
        for (int kk = 0; kk < 2; ++kk) {
            bf16x8 af[4], bfr[4];
            #pragma unroll
            for (int i = 0; i < 4; ++i)
                af[i] = *(const bf16x8*)&sA[wm + i * 16 + lm][kk * 32 + lq * 8];
            #pragma unroll
            for (int j = 0; j < 4; ++j)
                bfr[j] = *(const bf16x8*)&sB[wn + j * 16 + lm][kk * 32 + lq * 8];
            #pragma unroll
            for (int i = 0; i < 4; ++i)
                #pragma unroll
                for (int j = 0; j < 4; ++j)
                    acc[i][j] = __builtin_amdgcn_mfma_f32_16x16x32_bf16(af[i], bfr[j], acc[i][j], 0, 0, 0);
        }
        __syncthreads();
    }

    if constexpr (DOGELU) {
        #pragma unroll
        for (int i = 0; i < 4; ++i) {
            int gm = row0 + wm + i * 16 + lq * 4;
            #pragma unroll
            for (int j = 0; j < 4; ++j) {
                int gn = n0 + wn + j * 16 + lm;
                float bb = Bi[gn];
                #pragma unroll
                for (int r = 0; r < 4; ++r) {
                    float v = acc[i][j][r] + bb;
                    v = 0.5f * v * (1.0f + erff(v * 0.70710678118654752f));  // exact gelu
                    Hout[(size_t)(gm + r) * ND + gn] = f2bf(v);
                }
            }
        }
    } else {
        #pragma unroll
        for (int i = 0; i < 4; ++i) {
            int gmb = row0 + wm + i * 16 + lq * 4;
            #pragma unroll
            for (int r = 0; r < 4; ++r) {
                int gm = gmb + r;
                float sc = row_score[gm];
                if (sc != 0.0f) {
                    int t = row_tok[gm];
                    float* dst = Cout + (size_t)t * D_DIM;
                    #pragma unroll
                    for (int j = 0; j < 4; ++j) {
                        int gn = n0 + wn + j * 16 + lm;
                        float v = (acc[i][j][r] + Bi[gn]) * sc;
                        atomicAdd(dst + gn, v);
                    }
                }
            }
        }
    }
}

// -------------------------------------------------------------- launch ------
extern "C" void kernel_launch(void* const* d_in, const int* in_sizes, int n_in,
                              void* d_out, int out_size, void* d_ws, size_t ws_size,
                              hipStream_t stream)
{
    const float* x      = (const float*)d_in[0];
    const float* gate_w = (const float*)d_in[1];
    const float* sh1_w  = (const float*)d_in[2];
    const float* sh1_b  = (const float*)d_in[3];
    const float* sh2_w  = (const float*)d_in[4];
    const float* sh2_b  = (const float*)d_in[5];
    const float* e1_w   = (const float*)d_in[6];
    const float* e1_b   = (const float*)d_in[7];
    const float* e2_w   = (const float*)d_in[8];
    const float* e2_b   = (const float*)d_in[9];
    float* out = (float*)d_out;

    char* ws = (char*)d_ws;
    int*    cnt       = (int*)(ws + 0);                       // 65 ints
    float*  prob_sum  = (float*)(ws + 1024);                  // 64 f
    int*    off       = (int*)(ws + 2048);                    // 66 ints
    int*    total_t   = (int*)(ws + 3072);                    // 1 int
    int*    tile_exp  = (int*)(ws + 4096);                    // 288 ints
    int*    tok_of    = (int*)(ws + 8192);                    // 64*1536 ints
    float*  sc_of     = (float*)(ws + 8192 + (size_t)64 * CAP * 4);
    int*    row_tok   = (int*)(ws + 8192 + (size_t)2 * 64 * CAP * 4);
    float*  row_score = (float*)(ws + 8192 + (size_t)2 * 64 * CAP * 4 + (size_t)MAXROWS * 4);
    ushort* Xg        = (ushort*)(ws + (size_t)2 * 1024 * 1024);                      // 56.6 MB
    ushort* Hbuf      = (ushort*)(ws + (size_t)2 * 1024 * 1024 + (size_t)MAXROWS * 768 * 2); // 113 MB

    hipMemsetAsync(ws, 0, 2048, stream);                       // cnt + prob_sum
    hipMemsetAsync(d_out, 0, (size_t)out_size * 4, stream);    // accumulation target

    gate_kernel<<<T_TOKENS / 16, 256, 0, stream>>>(x, gate_w, cnt, prob_sum, tok_of, sc_of);
    stats_kernel<<<1, 256, 0, stream>>>(cnt, prob_sum, off, total_t, tile_exp, out + (size_t)T_TOKENS * D_DIM);
    gather_kernel<<<MAXROWS, 192, 0, stream>>>(x, off, cnt, tile_exp, total_t, tok_of, sc_of, Xg, row_tok, row_score);

    dim3 g1(MAXTILES, H_DIM / 128);
    gemm_kernel<D_DIM, H_DIM, true><<<g1, 256, 0, stream>>>(
        Xg, e1_w, sh1_w, e1_b, sh1_b, total_t, tile_exp, Hbuf, nullptr, nullptr, nullptr);

    dim3 g2(MAXTILES, D_DIM / 128);
    gemm_kernel<H_DIM, D_DIM, false><<<g2, 256, 0, stream>>>(
        Hbuf, e2_w, sh2_w, e2_b, sh2_b, total_t, tile_exp, nullptr, out, row_tok, row_score);
}